// Round 7
// baseline (4474.837 us; speedup 1.0000x reference)
//
#include <hip/hip_runtime.h>

#define TT 512
#define BSZ 64
#define DD 512
#define HH 512
#define NGROUP 4
#define GBLK 64        // blocks per group
#define GBATCH 16      // batches per group
#define NT 512         // threads per block

// part layout strides (floats), engineered conflict-free:
//  write lanes (4 sp x 2 par x 8 u): bank = (8sp + 16par + 8gi + u) % 32 -> 2-way (free)
//  cell lanes (16 bbu x 8 jju):      bank = (4bbu + jju + C) % 32       -> 2-way (free)
#define PART_SP 40
#define PART_BB 1284   // >= 32*40, and PART_BB % 32 == 4

struct Params {
    const float* X;
    const float* Wx[4];   // W_xi, W_xf, W_xo, W_xc   [D][H] row-major
    const float* Wh[4];   // W_hi, W_hf, W_ho, W_hc   [H][H] row-major
    const float* bias[4]; // b_i, b_f, b_o, b_c       [H]
    float* Y;             // [B][T][H]
    float* hbuf;          // ws: 2 * B * H floats (double buffer)
    unsigned int* ctr;    // ws: NGROUP counters, 64-uint padded
};

__device__ __forceinline__ float fast_sigmoid(float x) {
    return 1.0f / (1.0f + __expf(-x));
}

__device__ __forceinline__ float fast_tanh(float x) {
    float ax = fabsf(x);
    float e  = __expf(-2.0f * ax);
    float r  = (1.0f - e) / (1.0f + e);
    return copysignf(r, x);
}

// xor-8 pair-sum on the VALU pipe via DPP row_ror:8 (lane l <-> l^8 within each
// 16-lane row). MUST stay off the LDS pipe.
__device__ __forceinline__ float dpp_xor8_add(float v) {
    int pv = __builtin_amdgcn_update_dpp(0, __float_as_int(v),
                                         0x128 /*row_ror:8*/, 0xf, 0xf, true);
    return v + __int_as_float(pv);
}

// hbuf/ctr are accessed ONLY via cache-bypassing (agent-scope relaxed) ops in
// the main kernel, so the init writes must also be write-through.
__global__ void init_ws(float* hbuf, unsigned int* ctr) {
    int i = blockIdx.x * blockDim.x + threadIdx.x;
    int stride = gridDim.x * blockDim.x;
    for (int k = i; k < 2 * BSZ * HH; k += stride)
        __hip_atomic_store(&hbuf[k], 0.0f, __ATOMIC_RELAXED, __HIP_MEMORY_SCOPE_AGENT);
    if (i < 8 * 64)
        __hip_atomic_store(&ctr[i], 0u, __ATOMIC_RELAXED, __HIP_MEMORY_SCOPE_AGENT);
}

// Persistent LSTM, R7: SOFTWARE-PIPELINED STEP on the R6 fan-out structure.
// 256 blocks x 512 threads, 144.3 KB LDS -> 1 block/CU (proven residency).
//
// R6 (3506us, 7.2us/step) left ~4-5us/step of serialized latency: the chain
// [spin -> 8 IF h-loads -> hs write -> barrier -> h-FMA -> reduce -> cell ->
// publish] is fully serial, and next step's x staging waits for it. This
// version (T14 async-split on both staging streams):
//   A. x-proj HALF 1 (k4=0) before the spin  [absorbs inter-block skew]
//   B. spin, barrier
//   C. ISSUE 8 h IF-loads + 4 x(t+1) global loads into regs (no wait);
//      sched_barrier(0) pins issue before the next FMA region
//   D. x-proj HALF 2 (k4=1)                  [covers the IF load latency]
//   E. hreg->hs (vmcnt waits h loads only), barrier
//   G. h-FMA  H. reduce+part
//   I. xreg->xs (xs dead since E-barrier)    [x-stage costs 0 serial time]
//   J. barrier  K. cell update  L. barrier  M. publish
// Barriers 5 -> 4 per step.
//
// SPILL TRIPWIRE: VGPR ~150-170 expected (R6=124, +32 staging regs). If
// VGPR_Count=64 or WRITE_SIZE >> 135 MB: compiler pathology, revert staging.
// NT=1024 remains POISONED (R3/R4). 2-blocks/CU residency remains FORBIDDEN (R5).
//
// COHERENCE (proven): h exchange is IF-coherent, ZERO fences. Producer:
// relaxed agent store (write-through). __syncthreads drains vmcnt. tid0
// relaxed fetch_add publish; consumer tid0 relaxed spin; h staged via relaxed
// agent u64 loads (bypass L1/L2, served by IF).
__global__ __launch_bounds__(NT, 1) void lstm_persist(Params p) {
    __shared__ float xs[GBATCH * DD];        // 32 KB: x_t, 16 batches
    __shared__ float hs[GBATCH * HH];        // 32 KB: h_{t-1}, 16 batches
    __shared__ float part[16 * PART_BB];     // 80.25 KB: partials

    const int bid  = blockIdx.x;
    // XCD-pair swizzle (XCD assumed = bid & 7)
    const int g    = (bid & 7) >> 1;               // group 0..3 -> XCDs {2g,2g+1}
    const int k    = ((bid >> 3) << 1) | (bid & 1); // block-in-group 0..63
    const int tid  = threadIdx.x;
    const int u    = tid & 7;              // unit-in-block 0..7
    const int s    = tid >> 3;             // K-slice 0..63
    const int kb   = s * 8;                // K start (8 rows/thread)
    const int jc   = k * 8 + u;            // column in each gate's weight matrix
    const int b0   = g * GBATCH;

    // ---- one-time: weights into registers (4 gates x 8 k, x and h) ----
    float4 wx4[4][2], wh4[4][2];
#pragma unroll
    for (int g4 = 0; g4 < 4; ++g4) {
        const float* WxG = p.Wx[g4];
        const float* WhG = p.Wh[g4];
#pragma unroll
        for (int k4 = 0; k4 < 2; ++k4) {
            int kk = kb + k4 * 4;
            wx4[g4][k4] = make_float4(WxG[(kk + 0) * HH + jc], WxG[(kk + 1) * HH + jc],
                                      WxG[(kk + 2) * HH + jc], WxG[(kk + 3) * HH + jc]);
            wh4[g4][k4] = make_float4(WhG[(kk + 0) * HH + jc], WhG[(kk + 1) * HH + jc],
                                      WhG[(kk + 2) * HH + jc], WhG[(kk + 3) * HH + jc]);
        }
    }

    // Cell-update thread state (threads 0..127): (batch bbu, unit jju)
    const int bbu = tid >> 3;              // 0..15 (for tid<128)
    const int jju = tid & 7;
    const int ju  = k * 8 + jju;
    float cst = 0.0f;
    float bI = 0.f, bF = 0.f, bO = 0.f, bC = 0.f;
    if (tid < 128) {
        bI = p.bias[0][ju];
        bF = p.bias[1][ju];
        bO = p.bias[2][ju];
        bC = p.bias[3][ju];
    }

    unsigned int* ctrp = p.ctr + g * 64;
    const float4* xsrc = (const float4*)p.X;
    float4* xs4 = (float4*)xs;
    float4* hs4 = (float4*)hs;
    unsigned long long* hsu = (unsigned long long*)hs;

#define ACC4(A, V, W) \
    A = fmaf((V).x, (W).x, A); A = fmaf((V).y, (W).y, A); \
    A = fmaf((V).z, (W).z, A); A = fmaf((V).w, (W).w, A);

    // ---- prologue: stage x(0) ----
#pragma unroll
    for (int uu = 0; uu < 4; ++uu) {
        int idx = tid + uu * NT;           // 0..2047 (float4 index)
        int b   = idx >> 7;                // 0..15
        int dd  = idx & 127;               // float4 within row
        xs4[b * 128 + dd] = xsrc[((size_t)(b0 + b) * TT + 0) * 128 + dd];
    }
    __syncthreads();

    for (int t = 0; t < TT; ++t) {
        // ---- A. x-projection HALF 1 (k4=0): skew absorber ----
        float acc[4][16];
#pragma unroll
        for (int g4 = 0; g4 < 4; ++g4)
#pragma unroll
            for (int bb = 0; bb < 16; ++bb) acc[g4][bb] = 0.0f;
#pragma unroll
        for (int bb = 0; bb < 16; ++bb) {
            float4 xv = xs4[bb * 128 + s * 2 + 0];        // 8-lane broadcast
            ACC4(acc[0][bb], xv, wx4[0][0]);
            ACC4(acc[1][bb], xv, wx4[1][0]);
            ACC4(acc[2][bb], xv, wx4[2][0]);
            ACC4(acc[3][bb], xv, wx4[3][0]);
            if ((bb & 3) == 3) __builtin_amdgcn_sched_barrier(0);
        }

        // ---- B. wait for h_{t-1}: tid0-only relaxed spin (IF read, no fence) ----
        if (tid == 0) {
            const unsigned int need = (unsigned int)(GBLK * t);
            while (__hip_atomic_load(ctrp, __ATOMIC_RELAXED, __HIP_MEMORY_SCOPE_AGENT) < need) {
                __builtin_amdgcn_s_sleep(2);
            }
        }
        __syncthreads();

        // ---- C. ISSUE long-latency loads (no wait): h from IF, x(t+1) from L2 ----
        unsigned long long hreg[8];
        {
            const unsigned long long* hsrc =
                (const unsigned long long*)(p.hbuf + (size_t)(t & 1) * BSZ * HH);
#pragma unroll
            for (int uu = 0; uu < 8; ++uu) {
                int idx = tid + uu * NT;       // 0..4095 (u64 index)
                int b   = idx >> 8;            // 0..15
                int d   = idx & 255;
                hreg[uu] = __hip_atomic_load(&hsrc[(size_t)(b0 + b) * 256 + d],
                                             __ATOMIC_RELAXED, __HIP_MEMORY_SCOPE_AGENT);
            }
        }
        float4 xreg[4];
        if (t + 1 < TT) {
#pragma unroll
            for (int uu = 0; uu < 4; ++uu) {
                int idx = tid + uu * NT;       // 0..2047 (float4 index)
                int b   = idx >> 7;
                int dd  = idx & 127;
                xreg[uu] = xsrc[((size_t)(b0 + b) * TT + (t + 1)) * 128 + dd];
            }
        }
        __builtin_amdgcn_sched_barrier(0);     // pin load issue before the FMA region

        // ---- D. x-projection HALF 2 (k4=1): covers the in-flight load latency ----
#pragma unroll
        for (int bb = 0; bb < 16; ++bb) {
            float4 xv = xs4[bb * 128 + s * 2 + 1];        // 8-lane broadcast
            ACC4(acc[0][bb], xv, wx4[0][1]);
            ACC4(acc[1][bb], xv, wx4[1][1]);
            ACC4(acc[2][bb], xv, wx4[2][1]);
            ACC4(acc[3][bb], xv, wx4[3][1]);
            if ((bb & 3) == 3) __builtin_amdgcn_sched_barrier(0);
        }

        // ---- E. hreg -> hs (waits only the h loads: they are oldest in vmcnt) ----
#pragma unroll
        for (int uu = 0; uu < 8; ++uu)
            hsu[tid + uu * NT] = hreg[uu];
        __syncthreads();                       // hs ready; all xs(t) reads done

        // ---- G. recurrent FMAs ----
#pragma unroll
        for (int k4 = 0; k4 < 2; ++k4) {
#pragma unroll
            for (int bb = 0; bb < 16; ++bb) {
                float4 hv = hs4[bb * 128 + s * 2 + k4];   // 8-lane broadcast
                ACC4(acc[0][bb], hv, wh4[0][k4]);
                ACC4(acc[1][bb], hv, wh4[1][k4]);
                ACC4(acc[2][bb], hv, wh4[2][k4]);
                ACC4(acc[3][bb], hv, wh4[3][k4]);
                if ((bb & 3) == 3) __builtin_amdgcn_sched_barrier(0);
            }
        }

        // ---- H. DPP xor8 pair-sum (VALU), then write 32 sp-slices.
        //      s even -> gates {0,1}; s odd -> {2,3}. Static acc indices. ----
#pragma unroll
        for (int g4 = 0; g4 < 4; ++g4)
#pragma unroll
            for (int bb = 0; bb < 16; ++bb)
                acc[g4][bb] = dpp_xor8_add(acc[g4][bb]);
        {
            const int sp = s >> 1;             // 0..31
            float* dst = &part[sp * PART_SP + (s & 1) * 16 + u];
            if ((s & 1) == 0) {
#pragma unroll
                for (int bb = 0; bb < 16; ++bb) {
                    dst[bb * PART_BB + 0] = acc[0][bb];
                    dst[bb * PART_BB + 8] = acc[1][bb];
                }
            } else {
#pragma unroll
                for (int bb = 0; bb < 16; ++bb) {
                    dst[bb * PART_BB + 0] = acc[2][bb];
                    dst[bb * PART_BB + 8] = acc[3][bb];
                }
            }
        }

        // ---- I. xreg -> xs for step t+1 (xs dead since the E-barrier) ----
        if (t + 1 < TT) {
#pragma unroll
            for (int uu = 0; uu < 4; ++uu) {
                int idx = tid + uu * NT;
                int b   = idx >> 7;
                int dd  = idx & 127;
                xs4[b * 128 + dd] = xreg[uu];
            }
        }
        __syncthreads();                       // J: part ready AND xs(t+1) ready

        // ---- K. cell update (2 waves: 16 batches x 8 units) ----
        if (tid < 128) {
            float v0 = bI, v1 = bF, v2 = bO, v3 = bC;
            const float* pr = &part[bbu * PART_BB + jju];
#pragma unroll
            for (int ss = 0; ss < 32; ++ss) {
                v0 += pr[ss * PART_SP + 0];
                v1 += pr[ss * PART_SP + 8];
                v2 += pr[ss * PART_SP + 16];
                v3 += pr[ss * PART_SP + 24];
            }
            float I  = fast_sigmoid(v0);
            float F  = fast_sigmoid(v1);
            float O  = fast_sigmoid(v2);
            float Cd = fast_tanh(v3);
            cst = fmaf(F, cst, I * Cd);
            float h = O * fast_tanh(cst);
            // write-through to the IF (coherence point)
            __hip_atomic_store(&p.hbuf[(size_t)((t + 1) & 1) * BSZ * HH + (b0 + bbu) * HH + ju],
                               h, __ATOMIC_RELAXED, __HIP_MEMORY_SCOPE_AGENT);
            p.Y[((size_t)(b0 + bbu) * TT + t) * HH + ju] = h;
        }
        __syncthreads();   // L: drains vmcnt: h stores complete at the IF

        // ---- M. publish: tid0 RELAXED add (ordering via the vmcnt drain) ----
        if (tid == 0) {
            __hip_atomic_fetch_add(ctrp, 1u, __ATOMIC_RELAXED, __HIP_MEMORY_SCOPE_AGENT);
        }
    }
#undef ACC4
}

extern "C" void kernel_launch(void* const* d_in, const int* in_sizes, int n_in,
                              void* d_out, int out_size, void* d_ws, size_t ws_size,
                              hipStream_t stream) {
    Params p;
    p.X       = (const float*)d_in[0];
    p.Wx[0]   = (const float*)d_in[1];
    p.Wh[0]   = (const float*)d_in[2];
    p.bias[0] = (const float*)d_in[3];
    p.Wx[1]   = (const float*)d_in[4];
    p.Wh[1]   = (const float*)d_in[5];
    p.bias[1] = (const float*)d_in[6];
    p.Wx[2]   = (const float*)d_in[7];
    p.Wh[2]   = (const float*)d_in[8];
    p.bias[2] = (const float*)d_in[9];
    p.Wx[3]   = (const float*)d_in[10];
    p.Wh[3]   = (const float*)d_in[11];
    p.bias[3] = (const float*)d_in[12];
    p.Y       = (float*)d_out;
    p.hbuf    = (float*)d_ws;
    p.ctr     = (unsigned int*)((char*)d_ws + (size_t)2 * BSZ * HH * sizeof(float));

    // ws is poisoned 0xAA before every timed launch: zero h0 double-buffer + counters
    init_ws<<<64, 256, 0, stream>>>(p.hbuf, p.ctr);

    lstm_persist<<<dim3(256), dim3(NT), 0, stream>>>(p);
}

// Round 10
// 3519.235 us; speedup vs baseline: 1.2715x; 1.2715x over previous
//
#include <hip/hip_runtime.h>

#define TT 512
#define BSZ 64
#define DD 512
#define HH 512
#define NGROUP 4
#define GBLK 64        // blocks per group
#define GBATCH 16      // batches per group
#define NT 512         // threads per block

// part layout strides (floats), engineered conflict-free:
//  write lanes (4 sp x 2 par x 8 u): 2-way aliasing (free)
//  cell lanes (16 bbu x 8 jju): 2-way aliasing (free)
#define PART_SP 40
#define PART_BB 1284   // >= 32*40, and PART_BB % 32 == 4

struct Params {
    const float* X;
    const float* Wx[4];   // W_xi, W_xf, W_xo, W_xc   [D][H] row-major
    const float* Wh[4];   // W_hi, W_hf, W_ho, W_hc   [H][H] row-major
    const float* bias[4]; // b_i, b_f, b_o, b_c       [H]
    float* Y;             // [B][T][H]
    float* hbuf;          // ws: 2 * B * H floats (double buffer)
    unsigned int* ctr;    // ws: NGROUP counters, 64-uint padded
};

__device__ __forceinline__ float fast_sigmoid(float x) {
    return 1.0f / (1.0f + __expf(-x));
}

__device__ __forceinline__ float fast_tanh(float x) {
    float ax = fabsf(x);
    float e  = __expf(-2.0f * ax);
    float r  = (1.0f - e) / (1.0f + e);
    return copysignf(r, x);
}

// xor-8 pair-sum on the VALU pipe via DPP row_ror:8 (lane l <-> l^8 within each
// 16-lane row). MUST stay off the LDS pipe.
__device__ __forceinline__ float dpp_xor8_add(float v) {
    int pv = __builtin_amdgcn_update_dpp(0, __float_as_int(v),
                                         0x128 /*row_ror:8*/, 0xf, 0xf, true);
    return v + __int_as_float(pv);
}

// hbuf/ctr are accessed ONLY via cache-bypassing (agent-scope relaxed) ops in
// the main kernel, so the init writes must also be write-through.
__global__ void init_ws(float* hbuf, unsigned int* ctr) {
    int i = blockIdx.x * blockDim.x + threadIdx.x;
    int stride = gridDim.x * blockDim.x;
    for (int k = i; k < 2 * BSZ * HH; k += stride)
        __hip_atomic_store(&hbuf[k], 0.0f, __ATOMIC_RELAXED, __HIP_MEMORY_SCOPE_AGENT);
    if (i < 8 * 64)
        __hip_atomic_store(&ctr[i], 0u, __ATOMIC_RELAXED, __HIP_MEMORY_SCOPE_AGENT);
}

// Persistent LSTM, R10: EXACT R6 structure + protocol (proven 3506us on HW),
// with ONE provably-hang-free delta: the Y (HBM) store moved AFTER the
// publish, so the vmcnt drain that gates the publish no longer waits for the
// Y write ack. Y has no reader and no sync role — pure reordering.
//
// HARD RULES (paid for in container kills / regressions):
//  - NT=1024 POISONED (R3/R4: 64-VGPR allocation pathology -> 75GB spill).
//  - >1 block/CU residency FORBIDDEN (R5 deadlock); hipLaunchCooperativeKernel
//    FORBIDDEN (R8: graph-capture incompatible).
//  - Do NOT reorder R6's step schedule (R7: pre-spin work is free; moving it
//    into the post-spin chain cost 28%).
//  - R9's parallel-slot publish killed the container for UNIDENTIFIED reasons:
//    protocol changes beyond R6's proven fetch_add/spin are quarantined until
//    the R9 failure is understood. If THIS round also fails, the kernel is
//    exonerated (it is R6 +/- a store reorder) -> suspect infra.
//
// 256 blocks x 512 threads, 144.3 KB LDS -> 1 block/CU.
// COHERENCE (proven R1-R7): h exchange is IF-coherent, ZERO fences.
// Producer: relaxed agent store (write-through). __syncthreads drains vmcnt.
// tid0 relaxed fetch_add publish; consumer tid0 relaxed spin; h staged via
// relaxed agent u64 loads (bypass L1/L2, served by IF).
__global__ __launch_bounds__(NT, 1) void lstm_persist(Params p) {
    __shared__ float xs[GBATCH * DD];        // 32 KB: x_t, 16 batches
    __shared__ float hs[GBATCH * HH];        // 32 KB: h_{t-1}, 16 batches
    __shared__ float part[16 * PART_BB];     // 80.25 KB: partials

    const int bid  = blockIdx.x;
    // XCD-pair swizzle (XCD assumed = bid & 7)
    const int g    = (bid & 7) >> 1;               // group 0..3 -> XCDs {2g,2g+1}
    const int k    = ((bid >> 3) << 1) | (bid & 1); // block-in-group 0..63
    const int tid  = threadIdx.x;
    const int u    = tid & 7;              // unit-in-block 0..7
    const int s    = tid >> 3;             // K-slice 0..63
    const int kb   = s * 8;                // K start (8 rows/thread)
    const int jc   = k * 8 + u;            // column in each gate's weight matrix
    const int b0   = g * GBATCH;

    // ---- one-time: weights into registers (4 gates x 8 k, x and h) ----
    float4 wx4[4][2], wh4[4][2];
#pragma unroll
    for (int g4 = 0; g4 < 4; ++g4) {
        const float* WxG = p.Wx[g4];
        const float* WhG = p.Wh[g4];
#pragma unroll
        for (int k4 = 0; k4 < 2; ++k4) {
            int kk = kb + k4 * 4;
            wx4[g4][k4] = make_float4(WxG[(kk + 0) * HH + jc], WxG[(kk + 1) * HH + jc],
                                      WxG[(kk + 2) * HH + jc], WxG[(kk + 3) * HH + jc]);
            wh4[g4][k4] = make_float4(WhG[(kk + 0) * HH + jc], WhG[(kk + 1) * HH + jc],
                                      WhG[(kk + 2) * HH + jc], WhG[(kk + 3) * HH + jc]);
        }
    }

    // Cell-update thread state (threads 0..127): (batch bbu, unit jju)
    const int bbu = tid >> 3;              // 0..15 (for tid<128)
    const int jju = tid & 7;
    const int ju  = k * 8 + jju;
    float cst = 0.0f;
    float bI = 0.f, bF = 0.f, bO = 0.f, bC = 0.f;
    if (tid < 128) {
        bI = p.bias[0][ju];
        bF = p.bias[1][ju];
        bO = p.bias[2][ju];
        bC = p.bias[3][ju];
    }

    unsigned int* ctrp = p.ctr + g * 64;
    const float4* xsrc = (const float4*)p.X;
    float4* xs4 = (float4*)xs;
    float4* hs4 = (float4*)hs;

#define ACC4(A, V, W) \
    A = fmaf((V).x, (W).x, A); A = fmaf((V).y, (W).y, A); \
    A = fmaf((V).z, (W).z, A); A = fmaf((V).w, (W).w, A);

    for (int t = 0; t < TT; ++t) {
        // ---- 1. stage x_t (no cross-block dependency): 4 float4/thread ----
#pragma unroll
        for (int uu = 0; uu < 4; ++uu) {
            int idx = tid + uu * NT;           // 0..2047 (float4 index)
            int b   = idx >> 7;                // 0..15
            int dd  = idx & 127;               // float4 within row
            xs4[b * 128 + dd] = xsrc[((size_t)(b0 + b) * TT + t) * 128 + dd];
        }
        __syncthreads();

        // ---- 2. x-projection: each b128 broadcast feeds 16 FMAs ----
        float acc[4][16];
#pragma unroll
        for (int g4 = 0; g4 < 4; ++g4)
#pragma unroll
            for (int bb = 0; bb < 16; ++bb) acc[g4][bb] = 0.0f;
#pragma unroll
        for (int k4 = 0; k4 < 2; ++k4) {
#pragma unroll
            for (int bb = 0; bb < 16; ++bb) {
                float4 xv = xs4[bb * 128 + s * 2 + k4];   // 8-lane broadcast
                ACC4(acc[0][bb], xv, wx4[0][k4]);
                ACC4(acc[1][bb], xv, wx4[1][k4]);
                ACC4(acc[2][bb], xv, wx4[2][k4]);
                ACC4(acc[3][bb], xv, wx4[3][k4]);
                if ((bb & 3) == 3) __builtin_amdgcn_sched_barrier(0);
            }
        }

        // ---- 3. wait for h_{t-1}: tid0-only relaxed spin (IF read, no fence) ----
        if (tid == 0) {
            const unsigned int need = (unsigned int)(GBLK * t);
            while (__hip_atomic_load(ctrp, __ATOMIC_RELAXED, __HIP_MEMORY_SCOPE_AGENT) < need) {
                __builtin_amdgcn_s_sleep(2);
            }
        }
        __syncthreads();

        // ---- 4. stage h_{t-1}: u64 cache-bypassing loads, 8 in flight ----
        {
            const unsigned long long* hsrc =
                (const unsigned long long*)(p.hbuf + (size_t)(t & 1) * BSZ * HH);
            unsigned long long tmpu[8];
#pragma unroll
            for (int uu = 0; uu < 8; ++uu) {
                int idx = tid + uu * NT;       // 0..4095 (u64 index)
                int b   = idx >> 8;            // 0..15
                int d   = idx & 255;
                tmpu[uu] = __hip_atomic_load(&hsrc[(size_t)(b0 + b) * 256 + d],
                                             __ATOMIC_RELAXED, __HIP_MEMORY_SCOPE_AGENT);
            }
            unsigned long long* hsu = (unsigned long long*)hs;
#pragma unroll
            for (int uu = 0; uu < 8; ++uu)
                hsu[tid + uu * NT] = tmpu[uu];
        }
        __syncthreads();

        // ---- 5. recurrent FMAs ----
#pragma unroll
        for (int k4 = 0; k4 < 2; ++k4) {
#pragma unroll
            for (int bb = 0; bb < 16; ++bb) {
                float4 hv = hs4[bb * 128 + s * 2 + k4];   // 8-lane broadcast
                ACC4(acc[0][bb], hv, wh4[0][k4]);
                ACC4(acc[1][bb], hv, wh4[1][k4]);
                ACC4(acc[2][bb], hv, wh4[2][k4]);
                ACC4(acc[3][bb], hv, wh4[3][k4]);
                if ((bb & 3) == 3) __builtin_amdgcn_sched_barrier(0);
            }
        }

        // ---- 6. DPP xor8 pair-sum (VALU), then write 32 sp-slices.
        //      s even -> gates {0,1}; s odd -> {2,3}. Static acc indices. ----
#pragma unroll
        for (int g4 = 0; g4 < 4; ++g4)
#pragma unroll
            for (int bb = 0; bb < 16; ++bb)
                acc[g4][bb] = dpp_xor8_add(acc[g4][bb]);
        {
            const int sp = s >> 1;             // 0..31
            float* dst = &part[sp * PART_SP + (s & 1) * 16 + u];
            if ((s & 1) == 0) {
#pragma unroll
                for (int bb = 0; bb < 16; ++bb) {
                    dst[bb * PART_BB + 0] = acc[0][bb];
                    dst[bb * PART_BB + 8] = acc[1][bb];
                }
            } else {
#pragma unroll
                for (int bb = 0; bb < 16; ++bb) {
                    dst[bb * PART_BB + 0] = acc[2][bb];
                    dst[bb * PART_BB + 8] = acc[3][bb];
                }
            }
        }
        __syncthreads();

        // ---- 7. cell update (2 waves: 16 batches x 8 units); Y deferred ----
        float hout = 0.0f;
        if (tid < 128) {
            float v0 = bI, v1 = bF, v2 = bO, v3 = bC;
            const float* pr = &part[bbu * PART_BB + jju];
#pragma unroll
            for (int ss = 0; ss < 32; ++ss) {
                v0 += pr[ss * PART_SP + 0];
                v1 += pr[ss * PART_SP + 8];
                v2 += pr[ss * PART_SP + 16];
                v3 += pr[ss * PART_SP + 24];
            }
            float I  = fast_sigmoid(v0);
            float F  = fast_sigmoid(v1);
            float O  = fast_sigmoid(v2);
            float Cd = fast_tanh(v3);
            cst = fmaf(F, cst, I * Cd);
            hout = O * fast_tanh(cst);
            // write-through to the IF (coherence point)
            __hip_atomic_store(&p.hbuf[(size_t)((t + 1) & 1) * BSZ * HH + (b0 + bbu) * HH + ju],
                               hout, __ATOMIC_RELAXED, __HIP_MEMORY_SCOPE_AGENT);
        }
        __syncthreads();   // drains vmcnt: h stores complete at the IF
                           // (Y store NOT in this drain anymore)

        // ---- 8. publish: tid0 RELAXED fetch_add — byte-identical to R6 ----
        if (tid == 0) {
            __hip_atomic_fetch_add(ctrp, 1u, __ATOMIC_RELAXED, __HIP_MEMORY_SCOPE_AGENT);
        }

        // ---- 9. Y store AFTER publish: its HBM ack hides under the next
        //      step's pre-spin x-stage + x-projection ----
        if (tid < 128) {
            p.Y[((size_t)(b0 + bbu) * TT + t) * HH + ju] = hout;
        }
    }
#undef ACC4
}

extern "C" void kernel_launch(void* const* d_in, const int* in_sizes, int n_in,
                              void* d_out, int out_size, void* d_ws, size_t ws_size,
                              hipStream_t stream) {
    Params p;
    p.X       = (const float*)d_in[0];
    p.Wx[0]   = (const float*)d_in[1];
    p.Wh[0]   = (const float*)d_in[2];
    p.bias[0] = (const float*)d_in[3];
    p.Wx[1]   = (const float*)d_in[4];
    p.Wh[1]   = (const float*)d_in[5];
    p.bias[1] = (const float*)d_in[6];
    p.Wx[2]   = (const float*)d_in[7];
    p.Wh[2]   = (const float*)d_in[8];
    p.bias[2] = (const float*)d_in[9];
    p.Wx[3]   = (const float*)d_in[10];
    p.Wh[3]   = (const float*)d_in[11];
    p.bias[3] = (const float*)d_in[12];
    p.Y       = (float*)d_out;
    p.hbuf    = (float*)d_ws;
    p.ctr     = (unsigned int*)((char*)d_ws + (size_t)2 * BSZ * HH * sizeof(float));

    // ws is poisoned 0xAA before every timed launch: zero h0 double-buffer + counters
    init_ws<<<64, 256, 0, stream>>>(p.hbuf, p.ctr);

    lstm_persist<<<dim3(256), dim3(NT), 0, stream>>>(p);
}

// Round 11
// 3344.746 us; speedup vs baseline: 1.3379x; 1.0522x over previous
//
#include <hip/hip_runtime.h>

#define TT 512
#define BSZ 64
#define DD 512
#define HH 512
#define NGROUP 4
#define GBLK 64        // blocks per group
#define GBATCH 16      // batches per group
#define NT 512         // threads per block

// part layout strides (floats), engineered conflict-free:
//  write lanes (4 sp x 2 par x 8 u): 2-way aliasing (free)
//  cell lanes (16 bbu x 8 jju): 2-way aliasing (free)
#define PART_SP 40
#define PART_BB 1284   // >= 32*40, and PART_BB % 32 == 4

struct Params {
    const float* X;
    const float* Wx[4];   // W_xi, W_xf, W_xo, W_xc   [D][H] row-major
    const float* Wh[4];   // W_hi, W_hf, W_ho, W_hc   [H][H] row-major
    const float* bias[4]; // b_i, b_f, b_o, b_c       [H]
    float* Y;             // [B][T][H]
    float* hbuf;          // ws: 2 * B * H floats (double buffer)
    unsigned int* ctr;    // ws: NGROUP counters, 64-uint padded
};

__device__ __forceinline__ float fast_sigmoid(float x) {
    return 1.0f / (1.0f + __expf(-x));
}

__device__ __forceinline__ float fast_tanh(float x) {
    float ax = fabsf(x);
    float e  = __expf(-2.0f * ax);
    float r  = (1.0f - e) / (1.0f + e);
    return copysignf(r, x);
}

// xor-8 pair-sum on the VALU pipe via DPP row_ror:8 (lane l <-> l^8 within each
// 16-lane row). MUST stay off the LDS pipe.
__device__ __forceinline__ float dpp_xor8_add(float v) {
    int pv = __builtin_amdgcn_update_dpp(0, __float_as_int(v),
                                         0x128 /*row_ror:8*/, 0xf, 0xf, true);
    return v + __int_as_float(pv);
}

// hbuf/ctr are accessed ONLY via cache-bypassing (agent-scope relaxed) ops in
// the main kernel, so the init writes must also be write-through.
__global__ void init_ws(float* hbuf, unsigned int* ctr) {
    int i = blockIdx.x * blockDim.x + threadIdx.x;
    int stride = gridDim.x * blockDim.x;
    for (int k = i; k < 2 * BSZ * HH; k += stride)
        __hip_atomic_store(&hbuf[k], 0.0f, __ATOMIC_RELAXED, __HIP_MEMORY_SCOPE_AGENT);
    if (i < 8 * 64)
        __hip_atomic_store(&ctr[i], 0u, __ATOMIC_RELAXED, __HIP_MEMORY_SCOPE_AGENT);
}

// Persistent LSTM, R11: PER-WAVE h dependency on the R6/R10 base (3506us).
// 256 blocks x 512 threads, 144.3 KB LDS -> 1 block/CU.
//
// KEY DATAFLOW FACT: thread (u, s) reads only h columns [8s, 8s+8); wave w
// (slices 8w..8w+8) consumes EXACTLY h[.][64w..64w+64) — stageable entirely
// by that wave (8 u64 bypass loads/lane, same count as the old cooperative
// stage). So the post-spin and post-stage __syncthreads were pure
// over-synchronization. Now each wave: lane0 spins the PROVEN group counter
// (same object, same need=64t, same liveness as R6), stages ITS OWN region,
// and runs h-FMA on wave-local lgkmcnt. Barriers/step: 5 -> 3. Waves desync
// through the h phase, so one wave's IF latency overlaps another's FMA (the
// overlap R7 failed to get intra-wave, obtained across waves, without
// reordering the proven schedule).
//
// HARD RULES (paid for in container kills / regressions):
//  - NT=1024 POISONED (R3/R4: 64-VGPR pathology -> 75GB spill).
//  - >1 block/CU residency FORBIDDEN (R5); hipLaunchCooperativeKernel
//    FORBIDDEN (R8: graph-capture).
//  - Do NOT move work across the spin (R7: pre-spin work is free).
//  - R9's per-block-slot publish killed a container (unexplained; R10
//    exonerated the base). Novel protocol OBJECTS stay quarantined — this
//    round uses only R6-proven objects and access types.
//
// COHERENCE: unchanged. Producer h-stores write-through relaxed-agent (IF);
// __syncthreads drains vmcnt before tid0's relaxed fetch_add; ctr >= 64t
// observed => all h(t-1) at IF => bypass loads see them. hs stage->read is
// wave-local; hs WAR across steps is wave-sequential. Poll traffic is 8x R6
// (8 wave-leaders/block) -> s_sleep(4) halves the per-leader poll rate.
__global__ __launch_bounds__(NT, 1) void lstm_persist(Params p) {
    __shared__ float xs[GBATCH * DD];        // 32 KB: x_t, 16 batches
    __shared__ float hs[GBATCH * HH];        // 32 KB: h_{t-1}, 16 batches
    __shared__ float part[16 * PART_BB];     // 80.25 KB: partials

    const int bid  = blockIdx.x;
    // XCD-pair swizzle (XCD assumed = bid & 7)
    const int g    = (bid & 7) >> 1;               // group 0..3 -> XCDs {2g,2g+1}
    const int k    = ((bid >> 3) << 1) | (bid & 1); // block-in-group 0..63
    const int tid  = threadIdx.x;
    const int u    = tid & 7;              // unit-in-block 0..7
    const int s    = tid >> 3;             // K-slice 0..63
    const int kb   = s * 8;                // K start (8 rows/thread)
    const int jc   = k * 8 + u;            // column in each gate's weight matrix
    const int b0   = g * GBATCH;
    const int l    = tid & 63;             // lane in wave
    const int wv   = tid >> 6;             // wave 0..7

    // ---- one-time: weights into registers (4 gates x 8 k, x and h) ----
    float4 wx4[4][2], wh4[4][2];
#pragma unroll
    for (int g4 = 0; g4 < 4; ++g4) {
        const float* WxG = p.Wx[g4];
        const float* WhG = p.Wh[g4];
#pragma unroll
        for (int k4 = 0; k4 < 2; ++k4) {
            int kk = kb + k4 * 4;
            wx4[g4][k4] = make_float4(WxG[(kk + 0) * HH + jc], WxG[(kk + 1) * HH + jc],
                                      WxG[(kk + 2) * HH + jc], WxG[(kk + 3) * HH + jc]);
            wh4[g4][k4] = make_float4(WhG[(kk + 0) * HH + jc], WhG[(kk + 1) * HH + jc],
                                      WhG[(kk + 2) * HH + jc], WhG[(kk + 3) * HH + jc]);
        }
    }

    // Cell-update thread state (threads 0..127): (batch bbu, unit jju)
    const int bbu = tid >> 3;              // 0..15 (for tid<128)
    const int jju = tid & 7;
    const int ju  = k * 8 + jju;
    float cst = 0.0f;
    float bI = 0.f, bF = 0.f, bO = 0.f, bC = 0.f;
    if (tid < 128) {
        bI = p.bias[0][ju];
        bF = p.bias[1][ju];
        bO = p.bias[2][ju];
        bC = p.bias[3][ju];
    }

    unsigned int* ctrp = p.ctr + g * 64;
    const float4* xsrc = (const float4*)p.X;
    float4* xs4 = (float4*)xs;
    float4* hs4 = (float4*)hs;
    unsigned long long* hsu = (unsigned long long*)hs;

#define ACC4(A, V, W) \
    A = fmaf((V).x, (W).x, A); A = fmaf((V).y, (W).y, A); \
    A = fmaf((V).z, (W).z, A); A = fmaf((V).w, (W).w, A);

    for (int t = 0; t < TT; ++t) {
        // ---- 1. stage x_t (no cross-block dependency): 4 float4/thread ----
#pragma unroll
        for (int uu = 0; uu < 4; ++uu) {
            int idx = tid + uu * NT;           // 0..2047 (float4 index)
            int b   = idx >> 7;                // 0..15
            int dd  = idx & 127;               // float4 within row
            xs4[b * 128 + dd] = xsrc[((size_t)(b0 + b) * TT + t) * 128 + dd];
        }
        __syncthreads();                       // B1: xs ready (cross-wave)

        // ---- 2. x-projection: each b128 broadcast feeds 16 FMAs ----
        float acc[4][16];
#pragma unroll
        for (int g4 = 0; g4 < 4; ++g4)
#pragma unroll
            for (int bb = 0; bb < 16; ++bb) acc[g4][bb] = 0.0f;
#pragma unroll
        for (int k4 = 0; k4 < 2; ++k4) {
#pragma unroll
            for (int bb = 0; bb < 16; ++bb) {
                float4 xv = xs4[bb * 128 + s * 2 + k4];   // 8-lane broadcast
                ACC4(acc[0][bb], xv, wx4[0][k4]);
                ACC4(acc[1][bb], xv, wx4[1][k4]);
                ACC4(acc[2][bb], xv, wx4[2][k4]);
                ACC4(acc[3][bb], xv, wx4[3][k4]);
                if ((bb & 3) == 3) __builtin_amdgcn_sched_barrier(0);
            }
        }

        // ---- 3. PER-WAVE wait for h_{t-1}: lane0 holds its wave on the
        //      proven group counter (same object/need/liveness as R6) ----
        if (l == 0) {
            const unsigned int need = (unsigned int)(GBLK * t);
            while (__hip_atomic_load(ctrp, __ATOMIC_RELAXED, __HIP_MEMORY_SCOPE_AGENT) < need) {
                __builtin_amdgcn_s_sleep(4);
            }
        }
        // (wave reconverges here — no cross-wave barrier)

        // ---- 4. PER-WAVE h-stage: wave wv stages its own region
        //      h[.][64wv..64wv+64) = exactly what its slices read ----
        {
            const unsigned long long* hsrc =
                (const unsigned long long*)(p.hbuf + (size_t)(t & 1) * BSZ * HH);
            unsigned long long tmpu[8];
#pragma unroll
            for (int uu = 0; uu < 8; ++uu) {
                int idx = l + uu * 64;         // 0..511
                int b   = idx >> 5;            // 0..15
                int d   = idx & 31;            // u64 within the 32-u64 region
                tmpu[uu] = __hip_atomic_load(&hsrc[(size_t)(b0 + b) * 256 + 32 * wv + d],
                                             __ATOMIC_RELAXED, __HIP_MEMORY_SCOPE_AGENT);
            }
#pragma unroll
            for (int uu = 0; uu < 8; ++uu) {
                int idx = l + uu * 64;
                int b   = idx >> 5;
                int d   = idx & 31;
                hsu[b * 256 + 32 * wv + d] = tmpu[uu];
            }
        }
        // (stage->read is wave-local: compiler's lgkmcnt suffices, no barrier)

        // ---- 5. recurrent FMAs (reads only this wave's staged region) ----
#pragma unroll
        for (int k4 = 0; k4 < 2; ++k4) {
#pragma unroll
            for (int bb = 0; bb < 16; ++bb) {
                float4 hv = hs4[bb * 128 + s * 2 + k4];   // 8-lane broadcast
                ACC4(acc[0][bb], hv, wh4[0][k4]);
                ACC4(acc[1][bb], hv, wh4[1][k4]);
                ACC4(acc[2][bb], hv, wh4[2][k4]);
                ACC4(acc[3][bb], hv, wh4[3][k4]);
                if ((bb & 3) == 3) __builtin_amdgcn_sched_barrier(0);
            }
        }

        // ---- 6. DPP xor8 pair-sum (VALU), then write 32 sp-slices.
        //      s even -> gates {0,1}; s odd -> {2,3}. Static acc indices. ----
#pragma unroll
        for (int g4 = 0; g4 < 4; ++g4)
#pragma unroll
            for (int bb = 0; bb < 16; ++bb)
                acc[g4][bb] = dpp_xor8_add(acc[g4][bb]);
        {
            const int sp = s >> 1;             // 0..31
            float* dst = &part[sp * PART_SP + (s & 1) * 16 + u];
            if ((s & 1) == 0) {
#pragma unroll
                for (int bb = 0; bb < 16; ++bb) {
                    dst[bb * PART_BB + 0] = acc[0][bb];
                    dst[bb * PART_BB + 8] = acc[1][bb];
                }
            } else {
#pragma unroll
                for (int bb = 0; bb < 16; ++bb) {
                    dst[bb * PART_BB + 0] = acc[2][bb];
                    dst[bb * PART_BB + 8] = acc[3][bb];
                }
            }
        }
        __syncthreads();                       // B2: part ready (cross-wave)

        // ---- 7. cell update (2 waves: 16 batches x 8 units); Y deferred ----
        float hout = 0.0f;
        if (tid < 128) {
            float v0 = bI, v1 = bF, v2 = bO, v3 = bC;
            const float* pr = &part[bbu * PART_BB + jju];
#pragma unroll
            for (int ss = 0; ss < 32; ++ss) {
                v0 += pr[ss * PART_SP + 0];
                v1 += pr[ss * PART_SP + 8];
                v2 += pr[ss * PART_SP + 16];
                v3 += pr[ss * PART_SP + 24];
            }
            float I  = fast_sigmoid(v0);
            float F  = fast_sigmoid(v1);
            float O  = fast_sigmoid(v2);
            float Cd = fast_tanh(v3);
            cst = fmaf(F, cst, I * Cd);
            hout = O * fast_tanh(cst);
            // write-through to the IF (coherence point)
            __hip_atomic_store(&p.hbuf[(size_t)((t + 1) & 1) * BSZ * HH + (b0 + bbu) * HH + ju],
                               hout, __ATOMIC_RELAXED, __HIP_MEMORY_SCOPE_AGENT);
        }
        __syncthreads();                       // B3: drains vmcnt (h at IF)

        // ---- 8. publish: tid0 RELAXED fetch_add — byte-identical to R6 ----
        if (tid == 0) {
            __hip_atomic_fetch_add(ctrp, 1u, __ATOMIC_RELAXED, __HIP_MEMORY_SCOPE_AGENT);
        }

        // ---- 9. Y store AFTER publish: HBM ack hides under next pre-spin work ----
        if (tid < 128) {
            p.Y[((size_t)(b0 + bbu) * TT + t) * HH + ju] = hout;
        }
    }
#undef ACC4
}

extern "C" void kernel_launch(void* const* d_in, const int* in_sizes, int n_in,
                              void* d_out, int out_size, void* d_ws, size_t ws_size,
                              hipStream_t stream) {
    Params p;
    p.X       = (const float*)d_in[0];
    p.Wx[0]   = (const float*)d_in[1];
    p.Wh[0]   = (const float*)d_in[2];
    p.bias[0] = (const float*)d_in[3];
    p.Wx[1]   = (const float*)d_in[4];
    p.Wh[1]   = (const float*)d_in[5];
    p.bias[1] = (const float*)d_in[6];
    p.Wx[2]   = (const float*)d_in[7];
    p.Wh[2]   = (const float*)d_in[8];
    p.bias[2] = (const float*)d_in[9];
    p.Wx[3]   = (const float*)d_in[10];
    p.Wh[3]   = (const float*)d_in[11];
    p.bias[3] = (const float*)d_in[12];
    p.Y       = (float*)d_out;
    p.hbuf    = (float*)d_ws;
    p.ctr     = (unsigned int*)((char*)d_ws + (size_t)2 * BSZ * HH * sizeof(float));

    // ws is poisoned 0xAA before every timed launch: zero h0 double-buffer + counters
    init_ws<<<64, 256, 0, stream>>>(p.hbuf, p.ctr);

    lstm_persist<<<dim3(256), dim3(NT), 0, stream>>>(p);
}